// Round 7
// baseline (60.015 us; speedup 1.0000x reference)
//
#include <hip/hip_runtime.h>
#include <hip/hip_bf16.h>
#include <stdint.h>

typedef __bf16 bf16x8 __attribute__((ext_vector_type(8)));
typedef float  f32x4  __attribute__((ext_vector_type(4)));

#define LOG2E   1.4426950408889634f
#define LN2     0.6931471805599453f
#define LSE_OFF 60.0f
#define C_SCALED (LSE_OFF * LOG2E)   // 86.56170...

__device__ __forceinline__ void gload_lds16(const void* gsrc, void* ldst) {
    __builtin_amdgcn_global_load_lds(
        (const __attribute__((address_space(1))) unsigned int*)gsrc,
        (__attribute__((address_space(3))) unsigned int*)ldst,
        16, 0, 0);
}

// ---------------- kernel 1: permute + fp32->bf16 ----------------
// pred[b][n][c][h][w] -> A[m][c] row-major, SCALED by log2(e). gt -> B[m][c].
__global__ void convert_perm(const float* __restrict__ pred, const float* __restrict__ gt,
                             __bf16* __restrict__ Ab, __bf16* __restrict__ Bb)
{
    __shared__ __bf16 tile[256 * 17];
    const int slab = blockIdx.x & 511;
    const bool isA = blockIdx.x < 512;
    const float scale = isA ? LOG2E : 1.0f;
    const float* src = (isA ? pred : gt) + (size_t)slab * 4096;
    __bf16* dst = (isA ? Ab : Bb) + (size_t)slab * 4096;
    const int t = threadIdx.x;
    #pragma unroll
    for (int it = 0; it < 16; ++it) {
        const int e = it * 256 + t;          // c = e>>4, hw = e&15
        tile[(e >> 4) * 17 + (e & 15)] = (__bf16)(src[e] * scale);
    }
    __syncthreads();
    #pragma unroll
    for (int it = 0; it < 16; ++it) {
        const int o = it * 256 + t;          // hw = o>>8, c = o&255
        dst[(o >> 8) * 256 + (o & 255)] = tile[(o & 255) * 17 + (o >> 8)];
    }
}

// ---------------- kernel 2: fused GEMM + exp2-sum + diag, pipelined 4-phase ----------------
// 4-wave blocks (256 thr), tile 256i x 512j, A in VGPRs/AGPRs (64 i-rows/wave),
// B double-buffered in LDS (2x32KB) -> 2 blocks/CU. Per 64j step: 4 jj-band
// phases, register-double-buffered (gA/gB): band jj+1's 8 ds_read_b128 issue
// BEFORE band jj's 32-MFMA cluster, so LDS latency hides under MFMA. No manual
// lgkmcnt / sched_barrier (compiler emits counted lgkmcnt). ONE barrier/step.
__global__ __launch_bounds__(256) __attribute__((amdgpu_waves_per_eu(2, 2)))
void gemm_lse(const __bf16* __restrict__ Ab, const __bf16* __restrict__ Bb,
              float* __restrict__ rowsum_part, float* __restrict__ diagy)
{
    __shared__ __align__(16) char lds[65536];   // two 32KB B buffers
    const int tid  = threadIdx.x;
    const int lane = tid & 63;
    const int w    = tid >> 6;       // 0..3 (i split)
    const int l15  = lane & 15;
    const int lhi  = lane >> 4;

    const int jc = blockIdx.x & 15;  // 16 j-chunks of 512; jc%8 -> XCD (L2-local B)
    const int ib = blockIdx.x >> 4;  // 32 i-blocks of 256
    const int i0 = ib << 8;
    const int j0 = jc << 9;

    // ---- A fragments: 64 i-rows/wave, K=256 -> 4ii x 8ks bf16x8 (128 regs) ----
    bf16x8 pfr[4][8];
    {
        const char* base = (const char*)Ab + (size_t)(i0 + w * 64 + l15) * 512 + lhi * 16;
        #pragma unroll
        for (int ii = 0; ii < 4; ++ii)
            #pragma unroll
            for (int ks = 0; ks < 8; ++ks)
                pfr[ii][ks] = *(const bf16x8*)(base + ii * 16 * 512 + ks * 64);
    }

    const char* Bbase = (const char*)Bb + (size_t)j0 * 512;
    const int   rsw   = l15 << 4;            // read-side XOR swizzle
    const int   colb  = lhi * 16;

    // prologue stage of step 0 (8 gload_lds/thread, inverse-swizzled source)
    #pragma unroll
    for (int it = 0; it < 8; ++it) {
        const int ob = it * 4096 + w * 1024;
        const int ol = ob + lane * 16;
        const int sb = ol ^ (((ol >> 9) & 15) << 4);
        gload_lds16(Bbase + sb, lds + ob);
    }

    float rs[4] = {0.f, 0.f, 0.f, 0.f};
    const int ibase = i0 + w * 64;

    for (int js = 0; js < 8; ++js) {
        asm volatile("s_waitcnt vmcnt(0)" ::: "memory");   // stage loads (issued a full step ago) landed
        __builtin_amdgcn_s_barrier();

        const char* bufp  = lds + (js & 1) * 32768;
        char*       nbuf  = lds + ((js + 1) & 1) * 32768;
        const char* nsrc  = Bbase + (size_t)(js + 1) * 32768;
        const int   jbase = j0 + js * 64;

        // read 8 B-fragments (one j-band, all ks) into registers
        auto READ = [&](bf16x8 (&g)[8], int band) {
            const char* rp = bufp + (band * 16 + l15) * 512;
            #pragma unroll
            for (int ks = 0; ks < 8; ++ks)
                g[ks] = *(const bf16x8*)(rp + ((ks * 64 + colb) ^ rsw));
        };
        // 32-MFMA cluster: band j-frags x all 4 ii bands
        auto MM = [&](bf16x8 (&g)[8], f32x4 (&acc)[4]) {
            #pragma unroll
            for (int ii = 0; ii < 4; ++ii) acc[ii] = (f32x4){0.f, 0.f, 0.f, 0.f};
            __builtin_amdgcn_s_setprio(1);
            #pragma unroll
            for (int ks = 0; ks < 8; ++ks)
                #pragma unroll
                for (int ii = 0; ii < 4; ++ii)
                    acc[ii] = __builtin_amdgcn_mfma_f32_16x16x32_bf16(
                        g[ks], pfr[ii][ks], acc[ii], 0, 0, 0);
            __builtin_amdgcn_s_setprio(0);
        };
        // per-band epilogue: 16 exp2 (trans pipe) + diagonal capture
        auto EP = [&](f32x4 (&acc)[4], int jj) {
            const int jb = jbase + jj * 16;
            #pragma unroll
            for (int ii = 0; ii < 4; ++ii) {
                const f32x4 a = acc[ii];
                float s = __builtin_amdgcn_exp2f(a[0] - C_SCALED);
                s += __builtin_amdgcn_exp2f(a[1] - C_SCALED);
                s += __builtin_amdgcn_exp2f(a[2] - C_SCALED);
                s += __builtin_amdgcn_exp2f(a[3] - C_SCALED);
                if (ibase + ii * 16 == jb) {               // diagonal tile (wave-uniform)
                    const int ig = ibase + ii * 16 + l15;
                    const int rb = lhi * 4;
                    if (l15 == rb + 0) diagy[ig] = a[0];
                    if (l15 == rb + 1) diagy[ig] = a[1];
                    if (l15 == rb + 2) diagy[ig] = a[2];
                    if (l15 == rb + 3) diagy[ig] = a[3];
                }
                rs[ii] += s;
            }
        };

        bf16x8 gA[8], gB[8];
        f32x4  acc[4];

        READ(gA, 0);
        if (js < 7) {                       // stage next step (phase 0; 3 phases to land)
            #pragma unroll
            for (int it = 0; it < 8; ++it) {
                const int ob = it * 4096 + w * 1024;
                const int ol = ob + lane * 16;
                const int sb = ol ^ (((ol >> 9) & 15) << 4);
                gload_lds16(nsrc + sb, nbuf + ob);
            }
        }
        READ(gB, 1);  MM(gA, acc);  EP(acc, 0);   // jj=0 computes while band1 reads fly
        READ(gA, 2);  MM(gB, acc);  EP(acc, 1);
        READ(gB, 3);  MM(gA, acc);  EP(acc, 2);
                      MM(gB, acc);  EP(acc, 3);
        // all ds_reads consumed by MFMAs above; stage writes target the other buffer
    }

    // reduce partials across the 4 lhi groups; store to [i][slice=jc] layout
    #pragma unroll
    for (int ii = 0; ii < 4; ++ii) {
        float v = rs[ii];
        v += __shfl_xor(v, 16);
        v += __shfl_xor(v, 32);
        if (lhi == 0)
            rowsum_part[(size_t)(i0 + w * 64 + ii * 16 + l15) * 16 + jc] = v;
    }
}

// ---------------- kernel 3: per-row finish + per-block partial sums ----------------
__global__ __launch_bounds__(1024) void reduce_partial(const float* __restrict__ rowsum_part,
                                                       const float* __restrict__ diagy,
                                                       float* __restrict__ accum)
{
    const int i = blockIdx.x * 1024 + threadIdx.x;
    const f32x4* p = (const f32x4*)(rowsum_part + (size_t)i * 16);
    float s = 0.f;
    #pragma unroll
    for (int k = 0; k < 4; ++k) {
        const f32x4 v = p[k];
        s += (v[0] + v[1]) + (v[2] + v[3]);
    }
    float val = __log2f(s) - diagy[i];
    #pragma unroll
    for (int d = 1; d < 64; d <<= 1) val += __shfl_xor(val, d);
    __shared__ float red[16];
    if ((threadIdx.x & 63) == 0) red[threadIdx.x >> 6] = val;
    __syncthreads();
    if (threadIdx.x == 0) {
        float t = 0.f;
        #pragma unroll
        for (int k = 0; k < 16; ++k) t += red[k];
        accum[blockIdx.x] = t;     // plain store, no atomics / no memset needed
    }
}

__global__ void finalize(const float* __restrict__ accum, float* __restrict__ out)
{
    float t = 0.f;
    #pragma unroll
    for (int k = 0; k < 8; ++k) t += accum[k];
    out[0] = LSE_OFF + LN2 * t * (1.0f / 8192.0f);
}

// ---------------- launch ----------------
extern "C" void kernel_launch(void* const* d_in, const int* in_sizes, int n_in,
                              void* d_out, int out_size, void* d_ws, size_t ws_size,
                              hipStream_t stream) {
    const float* pred = (const float*)d_in[0];
    const float* gt   = (const float*)d_in[1];
    float* out = (float*)d_out;

    char* ws = (char*)d_ws;
    float*  accum       = (float*)(ws);             // 8 f32 (fully written)
    float*  diagy       = (float*)(ws + 0x1000);    // 8192 f32 (fully overwritten)
    float*  rowsum_part = (float*)(ws + 0x10000);   // 8192 x 16 f32 = 512KB (fully written)
    __bf16* Ab          = (__bf16*)(ws + 0x100000); // 4MB
    __bf16* Bb          = (__bf16*)(ws + 0x500000); // 4MB

    convert_perm<<<1024, 256, 0, stream>>>(pred, gt, Ab, Bb);
    gemm_lse<<<512, 256, 0, stream>>>(Ab, Bb, rowsum_part, diagy);
    reduce_partial<<<8, 1024, 0, stream>>>(rowsum_part, diagy, accum);
    finalize<<<1, 1, 0, stream>>>(accum, out);
}

// Round 8
// 52.319 us; speedup vs baseline: 1.1471x; 1.1471x over previous
//
#include <hip/hip_runtime.h>
#include <hip/hip_bf16.h>
#include <stdint.h>

typedef __bf16 bf16x8 __attribute__((ext_vector_type(8)));
typedef float  f32x4  __attribute__((ext_vector_type(4)));

#define LOG2E   1.4426950408889634f
#define LN2     0.6931471805599453f
#define LSE_OFF 60.0f
#define C_SCALED (LSE_OFF * LOG2E)   // 86.56170...

__device__ __forceinline__ void gload_lds16(const void* gsrc, void* ldst) {
    __builtin_amdgcn_global_load_lds(
        (const __attribute__((address_space(1))) unsigned int*)gsrc,
        (__attribute__((address_space(3))) unsigned int*)ldst,
        16, 0, 0);
}

// ---------------- kernel 1: permute + fp32->bf16 ----------------
// pred[b][n][c][h][w] -> A[m][c] row-major, SCALED by log2(e). gt -> B[m][c].
__global__ void convert_perm(const float* __restrict__ pred, const float* __restrict__ gt,
                             __bf16* __restrict__ Ab, __bf16* __restrict__ Bb)
{
    __shared__ __bf16 tile[256 * 17];
    const int slab = blockIdx.x & 511;
    const bool isA = blockIdx.x < 512;
    const float scale = isA ? LOG2E : 1.0f;
    const float* src = (isA ? pred : gt) + (size_t)slab * 4096;
    __bf16* dst = (isA ? Ab : Bb) + (size_t)slab * 4096;
    const int t = threadIdx.x;
    #pragma unroll
    for (int it = 0; it < 16; ++it) {
        const int e = it * 256 + t;          // c = e>>4, hw = e&15
        tile[(e >> 4) * 17 + (e & 15)] = (__bf16)(src[e] * scale);
    }
    __syncthreads();
    #pragma unroll
    for (int it = 0; it < 16; ++it) {
        const int o = it * 256 + t;          // hw = o>>8, c = o&255
        dst[(o >> 8) * 256 + (o & 255)] = tile[(o & 255) * 17 + (o >> 8)];
    }
}

// ---------------- kernel 2: fused GEMM + exp2-sum + diag ----------------
// 4-wave blocks (256 thr), tile 256i x 512j, A in regs (64 i-rows/wave),
// B double-buffered in LDS (2x32KB) -> 2 blocks/CU. Per 64j step:
// ONE barrier (head, after vmcnt(0) on stage loads issued a full step ago);
// 4 j-band compute clusters with a HALF-BAND register pipeline: band jj+1's
// reads issue in two 4-frag quads between 16-MFMA clusters (peak live
// g[8]+h[4]=48 frag regs vs R7's 64 -> no spill). No manual lgkmcnt: the
// compiler emits counted lgkm waits before the first consuming MFMA.
__global__ __launch_bounds__(256) __attribute__((amdgpu_waves_per_eu(2, 2)))
void gemm_lse(const __bf16* __restrict__ Ab, const __bf16* __restrict__ Bb,
              float* __restrict__ rowsum_part, float* __restrict__ diagy)
{
    __shared__ __align__(16) char lds[65536];   // two 32KB B buffers
    const int tid  = threadIdx.x;
    const int lane = tid & 63;
    const int w    = tid >> 6;       // 0..3 (i split)
    const int l15  = lane & 15;
    const int lhi  = lane >> 4;

    const int jc = blockIdx.x & 15;  // same-jc blocks are 16 apart -> same XCD (L2-local B)
    const int ib = blockIdx.x >> 4;  // 32 i-blocks of 256
    const int i0 = ib << 8;
    const int j0 = jc << 9;

    // ---- A fragments: 64 i-rows/wave, K=256 -> 4ii x 8ks bf16x8 (128 regs) ----
    bf16x8 pfr[4][8];
    {
        const char* base = (const char*)Ab + (size_t)(i0 + w * 64 + l15) * 512 + lhi * 16;
        #pragma unroll
        for (int ii = 0; ii < 4; ++ii)
            #pragma unroll
            for (int ks = 0; ks < 8; ++ks)
                pfr[ii][ks] = *(const bf16x8*)(base + ii * 16 * 512 + ks * 64);
    }

    const char* Bbase = (const char*)Bb + (size_t)j0 * 512;
    const int   rsw   = l15 << 4;            // read-side XOR swizzle
    const int   colb  = lhi * 16;
    const int   ibase = i0 + w * 64;

    // prologue stage of step 0
    #pragma unroll
    for (int it = 0; it < 8; ++it) {
        const int ob = it * 4096 + w * 1024;
        const int ol = ob + lane * 16;
        const int sb = ol ^ (((ol >> 9) & 15) << 4);
        gload_lds16(Bbase + sb, lds + ob);
    }

    float rs[4] = {0.f, 0.f, 0.f, 0.f};

#define READ8(G, BAND) { \
    const char* rp_ = bufp + ((BAND) * 16 + l15) * 512; \
    _Pragma("unroll") \
    for (int ks_ = 0; ks_ < 8; ++ks_) \
        G[ks_] = *(const bf16x8*)(rp_ + ((ks_ * 64 + colb) ^ rsw)); }

#define READ4(G, BAND, H) { \
    const char* rp_ = bufp + ((BAND) * 16 + l15) * 512; \
    _Pragma("unroll") \
    for (int k_ = 0; k_ < 4; ++k_) \
        G[(H) * 4 + k_] = *(const bf16x8*)(rp_ + ((((H) * 4 + k_) * 64 + colb) ^ rsw)); }

#define MM16(G, H) { \
    __builtin_amdgcn_s_setprio(1); \
    _Pragma("unroll") \
    for (int k_ = 0; k_ < 4; ++k_) { \
        const int ks_ = (H) * 4 + k_; \
        _Pragma("unroll") \
        for (int ii_ = 0; ii_ < 4; ++ii_) \
            acc[ii_] = __builtin_amdgcn_mfma_f32_16x16x32_bf16( \
                G[ks_], pfr[ii_][ks_], acc[ii_], 0, 0, 0); \
    } \
    __builtin_amdgcn_s_setprio(0); }

#define ZEROACC() { _Pragma("unroll") for (int ii_ = 0; ii_ < 4; ++ii_) acc[ii_] = (f32x4){0.f,0.f,0.f,0.f}; }

#define EP(JJ) { \
    const int jb_ = jbase + (JJ) * 16; \
    _Pragma("unroll") \
    for (int ii_ = 0; ii_ < 4; ++ii_) { \
        const f32x4 a_ = acc[ii_]; \
        float s_ = __builtin_amdgcn_exp2f(a_[0] - C_SCALED); \
        s_ += __builtin_amdgcn_exp2f(a_[1] - C_SCALED); \
        s_ += __builtin_amdgcn_exp2f(a_[2] - C_SCALED); \
        s_ += __builtin_amdgcn_exp2f(a_[3] - C_SCALED); \
        if (ibase + ii_ * 16 == jb_) { \
            const int ig_ = ibase + ii_ * 16 + l15; \
            const int rb_ = lhi * 4; \
            if (l15 == rb_ + 0) diagy[ig_] = a_[0]; \
            if (l15 == rb_ + 1) diagy[ig_] = a_[1]; \
            if (l15 == rb_ + 2) diagy[ig_] = a_[2]; \
            if (l15 == rb_ + 3) diagy[ig_] = a_[3]; \
        } \
        rs[ii_] += s_; \
    } }

    for (int js = 0; js < 8; ++js) {
        asm volatile("s_waitcnt vmcnt(0)" ::: "memory");  // stage loads (1 step old) landed
        __builtin_amdgcn_s_barrier();                     // the ONLY barrier per step

        const char* bufp  = lds + (js & 1) * 32768;
        char*       nbuf  = lds + ((js + 1) & 1) * 32768;
        const char* nsrc  = Bbase + (size_t)(js + 1) * 32768;
        const int   jbase = j0 + js * 64;

        bf16x8 g[8], h[8];
        f32x4  acc[4];

        READ8(g, 0);
        if (js < 7) {                     // stage next step: vmem, doesn't touch lgkm
            #pragma unroll
            for (int it = 0; it < 8; ++it) {
                const int ob = it * 4096 + w * 1024;
                const int ol = ob + lane * 16;
                const int sb = ol ^ (((ol >> 9) & 15) << 4);
                gload_lds16(nsrc + sb, nbuf + ob);
            }
        }

        ZEROACC(); READ4(h, 1, 0); MM16(g, 0); READ4(h, 1, 1); MM16(g, 1); EP(0);
        ZEROACC(); READ4(g, 2, 0); MM16(h, 0); READ4(g, 2, 1); MM16(h, 1); EP(1);
        ZEROACC(); READ4(h, 3, 0); MM16(g, 0); READ4(h, 3, 1); MM16(g, 1); EP(2);
        ZEROACC();                 MM16(h, 0);                 MM16(h, 1); EP(3);
    }

#undef READ8
#undef READ4
#undef MM16
#undef ZEROACC
#undef EP

    // reduce partials across the 4 lhi groups; store to [i][slice=jc] layout
    #pragma unroll
    for (int ii = 0; ii < 4; ++ii) {
        float v = rs[ii];
        v += __shfl_xor(v, 16);
        v += __shfl_xor(v, 32);
        if (lhi == 0)
            rowsum_part[(size_t)(i0 + w * 64 + ii * 16 + l15) * 16 + jc] = v;
    }
}

// ---------------- kernel 3: per-row finish + per-block partial sums ----------------
__global__ __launch_bounds__(1024) void reduce_partial(const float* __restrict__ rowsum_part,
                                                       const float* __restrict__ diagy,
                                                       float* __restrict__ accum)
{
    const int i = blockIdx.x * 1024 + threadIdx.x;
    const f32x4* p = (const f32x4*)(rowsum_part + (size_t)i * 16);
    float s = 0.f;
    #pragma unroll
    for (int k = 0; k < 4; ++k) {
        const f32x4 v = p[k];
        s += (v[0] + v[1]) + (v[2] + v[3]);
    }
    float val = __log2f(s) - diagy[i];
    #pragma unroll
    for (int d = 1; d < 64; d <<= 1) val += __shfl_xor(val, d);
    __shared__ float red[16];
    if ((threadIdx.x & 63) == 0) red[threadIdx.x >> 6] = val;
    __syncthreads();
    if (threadIdx.x == 0) {
        float t = 0.f;
        #pragma unroll
        for (int k = 0; k < 16; ++k) t += red[k];
        accum[blockIdx.x] = t;     // plain store, no atomics / no memset needed
    }
}

__global__ void finalize(const float* __restrict__ accum, float* __restrict__ out)
{
    float t = 0.f;
    #pragma unroll
    for (int k = 0; k < 8; ++k) t += accum[k];
    out[0] = LSE_OFF + LN2 * t * (1.0f / 8192.0f);
}

// ---------------- launch ----------------
extern "C" void kernel_launch(void* const* d_in, const int* in_sizes, int n_in,
                              void* d_out, int out_size, void* d_ws, size_t ws_size,
                              hipStream_t stream) {
    const float* pred = (const float*)d_in[0];
    const float* gt   = (const float*)d_in[1];
    float* out = (float*)d_out;

    char* ws = (char*)d_ws;
    float*  accum       = (float*)(ws);             // 8 f32 (fully written)
    float*  diagy       = (float*)(ws + 0x1000);    // 8192 f32 (fully overwritten)
    float*  rowsum_part = (float*)(ws + 0x10000);   // 8192 x 16 f32 = 512KB (fully written)
    __bf16* Ab          = (__bf16*)(ws + 0x100000); // 4MB
    __bf16* Bb          = (__bf16*)(ws + 0x500000); // 4MB

    convert_perm<<<1024, 256, 0, stream>>>(pred, gt, Ab, Bb);
    gemm_lse<<<512, 256, 0, stream>>>(Ab, Bb, rowsum_part, diagy);
    reduce_partial<<<8, 1024, 0, stream>>>(rowsum_part, diagy, accum);
    finalize<<<1, 1, 0, stream>>>(accum, out);
}